// Round 8
// baseline (144.529 us; speedup 1.0000x reference)
//
#include <hip/hip_runtime.h>

// ---------- bf16 helpers (raw ushort representation) ----------
__device__ __forceinline__ unsigned short f2b(float f) {
    unsigned int u = __builtin_bit_cast(unsigned int, f);
    u += 0x7fffu + ((u >> 16) & 1u);   // round-to-nearest-even
    return (unsigned short)(u >> 16);
}

typedef short bf16x8_t __attribute__((ext_vector_type(8)));
typedef float f32x4_t  __attribute__((ext_vector_type(4)));

#define LDS_PTR(p) ((__attribute__((address_space(3))) void*)(p))
#define GLB_PTR(p) ((const __attribute__((address_space(1))) void*)(p))

// Problem dims
#define NB   16384   // batch
#define AD   1024    // A dim
#define YD   128     // output dim
#define ND   256     // GEMM N = 2*YD
#define BM   32      // gemm rows per block

// =====================================================================
// Kernel 1: blocks [0,4096): one wave per row — 9 moments -> closed-form
//   bf fixed point (R2-validated math) -> write bff ONLY (no af store).
// blocks [4096,5120): Vt[n][a] = Kq[a,j]^2 * u[2a+j][y]  (bf16, K-major).
// =====================================================================
__global__ __launch_bounds__(256) void rowvt_kernel(
    const float* __restrict__ AT,     // [16384][1024] f32
    const float* __restrict__ Kq,     // [1024][2] f32
    const float* __restrict__ BTv,    // [2] f32
    const float* __restrict__ U,      // [2048][128] f32
    unsigned short* __restrict__ Vt,  // [256][1024] bf16 out
    float* __restrict__ bff)          // [16384][2] f32 out
{
    int bx = blockIdx.x;
    if (bx >= NB / 4) {
        int idx = (bx - NB / 4) * 256 + threadIdx.x;   // 0 .. 262143
        int n = idx >> 10;
        int a = idx & 1023;
        int j = n >> 7;
        int y = n & 127;
        float k  = Kq[2 * a + j];
        float uv = U[(size_t)(2 * a + j) * YD + y];
        Vt[idx] = f2b(k * k * uv);
        return;
    }
    int wid  = bx * 4 + (threadIdx.x >> 6);
    int lane = threadIdx.x & 63;
    const float* at = AT + (size_t)wid * AD;

    // lane holds cols a = c*256 + lane*4 + e (coalesced float4s)
    float ta[16], kp0[16], kp1[16];
#pragma unroll
    for (int c = 0; c < 4; ++c) {
        int base = c * 256 + lane * 4;
        float4 av = *(const float4*)(at + base);
        ta[c * 4 + 0] = av.x; ta[c * 4 + 1] = av.y;
        ta[c * 4 + 2] = av.z; ta[c * 4 + 3] = av.w;
        float4 k0 = *(const float4*)(Kq + 2 * base);
        float4 k1 = *(const float4*)(Kq + 2 * base + 4);
        kp0[c * 4 + 0] = k0.x * k0.x; kp1[c * 4 + 0] = k0.y * k0.y;
        kp0[c * 4 + 1] = k0.z * k0.z; kp1[c * 4 + 1] = k0.w * k0.w;
        kp0[c * 4 + 2] = k1.x * k1.x; kp1[c * 4 + 2] = k1.y * k1.y;
        kp0[c * 4 + 3] = k1.z * k1.z; kp1[c * 4 + 3] = k1.w * k1.w;
    }

    // moments: 0:M0 1:M1 2:M00 3:M01 4:M11 5:M000 6:M001 7:M011 8:M111
    float M[9];
#pragma unroll
    for (int i = 0; i < 9; ++i) M[i] = 0.f;
#pragma unroll
    for (int e = 0; e < 16; ++e) {
        float t = ta[e], p = kp0[e], q = kp1[e];
        float u0 = t * p, u1 = t * q;
        M[0] += u0; M[1] += u1;
        float u00 = u0 * p, u01 = u0 * q, u11 = u1 * q;
        M[2] += u00; M[3] += u01; M[4] += u11;
        M[5] += u00 * p; M[6] += u00 * q; M[7] += u01 * q; M[8] += u11 * q;
    }
#pragma unroll
    for (int i = 0; i < 9; ++i) {
        for (int m = 1; m < 64; m <<= 1) M[i] += __shfl_xor(M[i], m, 64);
    }

    float bt0 = BTv[0], bt1 = BTv[1];
    float bf0 = 0.f, bf1 = 0.f;
#pragma unroll
    for (int it = 0; it < 8; ++it) {
        float q00 = bf0 * bf0, q01 = bf0 * bf1, q11 = bf1 * bf1;
        float s0 = M[0] - (bf0 * M[2] + bf1 * M[3]) + (q00 * M[5] + 2.f * q01 * M[6] + q11 * M[7]);
        float s1 = M[1] - (bf0 * M[3] + bf1 * M[4]) + (q00 * M[6] + 2.f * q01 * M[7] + q11 * M[8]);
        bf0 = bt0 / (1.f + s0);
        bf1 = bt1 / (1.f + s1);
    }
    if (lane == 0) { bff[(size_t)wid * 2] = bf0; bff[(size_t)wid * 2 + 1] = bf1; }
}

// =====================================================================
// Kernel 2: GEMM + fused combine. Pre-loop: read raw AT f32 (L3-hot from
// kernel 1's pass), weight w = x*(x-1)+1 (R4-validated, single rounding
// f2b(a*w)), pack to pk registers. K-loop & epilogue identical to R7.
// BM=32, BN=256(full), BK=64; 512 blocks, 512 thr (8 waves).
// LDS: lB dbuf 64K + lAb dbuf 8K + bfs 256B = 72.25K -> 2 blocks/CU.
// =====================================================================
__global__ __launch_bounds__(512, 2) void gemm_kernel(
    const float* __restrict__ AT,            // [16384][1024] f32
    const float* __restrict__ Kq,            // [1024][2] f32
    const unsigned short* __restrict__ Bg,   // Vt [256][1024] bf16
    const float* __restrict__ bff,           // [16384][2]
    const float* __restrict__ bias,          // [128]
    float* __restrict__ out)                 // [16384][128] f32
{
    __shared__ __align__(16) unsigned short lB[2][256 * 64];  // 64 KB
    __shared__ __align__(16) unsigned short lAb[2][32 * 64];  // 8 KB
    __shared__ float bfs[BM][2];                              // 256 B

    const int t     = threadIdx.x;
    const int mtile = blockIdx.x;   // 0..511
    const int r     = t >> 4;       // row 0..31
    const int li    = t & 15;
    const int lane  = t & 63;
    const int w     = t >> 6;       // wave 0..7

    // ---- pre-loop: A f32 -> weighted bf16 pk registers (chunk c == K-tile c) ----
    const float* aRow = AT + (size_t)(mtile * BM + r) * AD + li * 4;
    const float2 cbf = *(const float2*)(bff + (size_t)(mtile * BM + r) * 2);
    unsigned int pk[16][2];
#pragma unroll
    for (int c = 0; c < 16; ++c) {
        int base = c * 64 + li * 4;
        float4 av = *(const float4*)(aRow + c * 64);
        float4 k0 = *(const float4*)(Kq + 2 * base);      // K[k][0..1], K[k+1][0..1]
        float4 k1 = *(const float4*)(Kq + 2 * base + 4);  // K[k+2..k+3]
        float ae[4] = {av.x, av.y, av.z, av.w};
        float pe[4] = {k0.x * k0.x, k0.z * k0.z, k1.x * k1.x, k1.z * k1.z};
        float qe[4] = {k0.y * k0.y, k0.w * k0.w, k1.y * k1.y, k1.w * k1.w};
        unsigned short rs[4];
#pragma unroll
        for (int e = 0; e < 4; ++e) {
            float x  = cbf.x * pe[e] + cbf.y * qe[e];
            float wg = x * (x - 1.f) + 1.f;       // 1 - x + x^2
            rs[e] = f2b(ae[e] * wg);
        }
        pk[c][0] = (unsigned int)rs[0] | ((unsigned int)rs[1] << 16);
        pk[c][1] = (unsigned int)rs[2] | ((unsigned int)rs[3] << 16);
    }
    if (t < BM) *(float2*)&bfs[t][0] = *(const float2*)(bff + (size_t)(mtile * BM + t) * 2);

    const unsigned short* gBp[4];
#pragma unroll
    for (int i = 0; i < 4; ++i) {
        int s = i * 512 + t;
        int n = s >> 3;
        int c = s & 7;
        gBp[i] = Bg + (size_t)n * AD + 8 * (c ^ (n & 7));  // slot s holds chunk (s&7)^(n&7)
    }
    // A write addr: tile chunk li>>1 of row r, half li&1 (swizzled)
    const int aws = (r * 8 + ((li >> 1) ^ (r & 7))) * 8 + (li & 1) * 4;

    // prologue: stage tile 0
#pragma unroll
    for (int i = 0; i < 4; ++i)
        __builtin_amdgcn_global_load_lds(GLB_PTR(gBp[i]), LDS_PTR(&lB[0][(i * 512 + t) * 8]), 16, 0, 0);
    *(uint2*)&lAb[0][aws] = make_uint2(pk[0][0], pk[0][1]);
    __syncthreads();

    f32x4_t acc[2][2];
#pragma unroll
    for (int i = 0; i < 2; ++i)
#pragma unroll
        for (int j = 0; j < 2; ++j) acc[i][j] = (f32x4_t){0.f, 0.f, 0.f, 0.f};

    const int rr = lane & 15, q4 = lane >> 4;

#pragma unroll
    for (int kt = 0; kt < 16; ++kt) {
        const int buf = kt & 1;
        if (kt + 1 < 16) {
#pragma unroll
            for (int i = 0; i < 4; ++i)
                __builtin_amdgcn_global_load_lds(GLB_PTR(gBp[i] + (kt + 1) * 64),
                                                 LDS_PTR(&lB[buf ^ 1][(i * 512 + t) * 8]), 16, 0, 0);
            *(uint2*)&lAb[buf ^ 1][aws] = make_uint2(pk[kt + 1][0], pk[kt + 1][1]);
        }
#pragma unroll
        for (int kk = 0; kk < 2; ++kk) {
            const int cq = kk * 4 + q4;
            bf16x8_t fa[2], fb[2];
#pragma unroll
            for (int i = 0; i < 2; ++i) {
                int m = i * 16 + rr;
                fa[i] = *(const bf16x8_t*)(&lAb[buf][(m * 8 + (cq ^ (m & 7))) * 8]);
            }
#pragma unroll
            for (int j = 0; j < 2; ++j) {
                int n = j * 128 + w * 16 + rr;
                fb[j] = *(const bf16x8_t*)(&lB[buf][(n * 8 + (cq ^ (n & 7))) * 8]);
            }
#pragma unroll
            for (int i = 0; i < 2; ++i)
#pragma unroll
                for (int j = 0; j < 2; ++j)
                    acc[i][j] = __builtin_amdgcn_mfma_f32_16x16x32_bf16(fa[i], fb[j], acc[i][j], 0, 0, 0);
        }
        __syncthreads();   // drains next tile's B loads + lAb write; protects buf reuse
    }

    // ---- epilogue: C/D layout col=lane&15 (n), row=q4*4+reg (m) ----
#pragma unroll
    for (int i = 0; i < 2; ++i) {
#pragma unroll
        for (int rt = 0; rt < 4; ++rt) {
            int ml = i * 16 + q4 * 4 + rt;
            int y  = w * 16 + rr;
            float v = bfs[ml][0] * acc[i][0][rt] + bfs[ml][1] * acc[i][1][rt] + bias[y];
            out[(size_t)(mtile * BM + ml) * YD + y] = v;
        }
    }
}

// =====================================================================
extern "C" void kernel_launch(void* const* d_in, const int* in_sizes, int n_in,
                              void* d_out, int out_size, void* d_ws, size_t ws_size,
                              hipStream_t stream) {
    const float* AT  = (const float*)d_in[0];  // [16384][1024] f32
    const float* Kq  = (const float*)d_in[1];  // [1024][2] f32
    const float* BTv = (const float*)d_in[2];  // [2] f32
    const float* U   = (const float*)d_in[3];  // [2048][128] f32
    const float* bia = (const float*)d_in[4];  // [128] f32
    float* out = (float*)d_out;

    char* ws = (char*)d_ws;
    unsigned short* Vt  = (unsigned short*)(ws);           // 512 KB bf16 [256][1024]
    float*          bff = (float*)(ws + 524288);           // 128 KB f32  [16384][2]

    rowvt_kernel<<<dim3(NB / 4 + 1024), dim3(256), 0, stream>>>(AT, Kq, BTv, U, Vt, bff);
    gemm_kernel<<<dim3(NB / BM), dim3(512), 0, stream>>>(AT, Kq, Vt, bff, bia, out);
}